// Round 1
// baseline (346.446 us; speedup 1.0000x reference)
//
#include <hip/hip_runtime.h>
#include <hip/hip_bf16.h>
#include <math.h>

#define NH 12
#define DH 64
#define BB 2
#define NN 2048
#define DM 768

typedef short v8s __attribute__((ext_vector_type(8)));
typedef float v4f __attribute__((ext_vector_type(4)));

__device__ __forceinline__ unsigned short f2bf(float f) {
    union { float f; unsigned u; } x; x.f = f;
    unsigned r = x.u + 0x7fffu + ((x.u >> 16) & 1u);
    return (unsigned short)(r >> 16);
}

// ---- cast x (fp32 -> bf16, layout-preserving) ----
__global__ __launch_bounds__(256) void cast_x_k(const float* __restrict__ in,
                                                unsigned short* __restrict__ out, int n) {
    int i = (blockIdx.x * 256 + threadIdx.x) * 4;
    if (i >= n) return;
    float4 v = *(const float4*)(in + i);
    ushort4 o;
    o.x = f2bf(v.x); o.y = f2bf(v.y); o.z = f2bf(v.z); o.w = f2bf(v.w);
    *(ushort4*)(out + i) = o;
}

// ---- cast + transpose the 4 weight matrices (768x768): out[c][k] = in[k][c] ----
__global__ __launch_bounds__(256) void cast_wT_k(const float* __restrict__ w0, const float* __restrict__ w1,
                                                 const float* __restrict__ w2, const float* __restrict__ w3,
                                                 unsigned short* __restrict__ o0, unsigned short* __restrict__ o1,
                                                 unsigned short* __restrict__ o2, unsigned short* __restrict__ o3) {
    const float* in; unsigned short* out;
    switch (blockIdx.y) {
        case 0: in = w0; out = o0; break;
        case 1: in = w1; out = o1; break;
        case 2: in = w2; out = o2; break;
        default: in = w3; out = o3; break;
    }
    int idx = blockIdx.x * 256 + threadIdx.x;   // 0 .. 589823
    int k = idx / 768, c = idx % 768;           // coalesced read along c
    out[c * 768 + k] = f2bf(in[idx]);
}

// ---- fused QKV projection: [4096,768] @ {wq,wk,wv} + bias ----
// q stored [B,H,N,D] bf16 with 0.125 scale folded; k stored [B,H,N,D]; v stored transposed [B,H,D,N]
__global__ __launch_bounds__(256) void qkv_gemm_k(
    const unsigned short* __restrict__ xb,
    const unsigned short* __restrict__ wqT, const unsigned short* __restrict__ wkT,
    const unsigned short* __restrict__ wvT,
    const float* __restrict__ bq, const float* __restrict__ bk, const float* __restrict__ bv,
    unsigned short* __restrict__ q, unsigned short* __restrict__ k, unsigned short* __restrict__ vT) {
    int ctile = blockIdx.x;            // 12 tiles of 64 cols
    int mtile = blockIdx.y;            // 64 tiles of 64 rows
    int w = threadIdx.x >> 6, l = threadIdx.x & 63;
    int row = mtile * 64 + w * 16 + (l & 15);
    int klane = 8 * (l >> 4);
    v4f zero = {0.f, 0.f, 0.f, 0.f};
    v4f acc[3][4];
#pragma unroll
    for (int m = 0; m < 3; m++)
#pragma unroll
        for (int ct = 0; ct < 4; ct++) acc[m][ct] = zero;

#pragma unroll 4
    for (int k0 = 0; k0 < 768; k0 += 32) {
        v8s a = *(const v8s*)(xb + row * 768 + k0 + klane);
#pragma unroll
        for (int ct = 0; ct < 4; ct++) {
            int col = ctile * 64 + ct * 16 + (l & 15);
            v8s b0 = *(const v8s*)(wqT + col * 768 + k0 + klane);
            v8s b1 = *(const v8s*)(wkT + col * 768 + k0 + klane);
            v8s b2 = *(const v8s*)(wvT + col * 768 + k0 + klane);
            acc[0][ct] = __builtin_amdgcn_mfma_f32_16x16x32_bf16(a, b0, acc[0][ct], 0, 0, 0);
            acc[1][ct] = __builtin_amdgcn_mfma_f32_16x16x32_bf16(a, b1, acc[1][ct], 0, 0, 0);
            acc[2][ct] = __builtin_amdgcn_mfma_f32_16x16x32_bf16(a, b2, acc[2][ct], 0, 0, 0);
        }
    }

#pragma unroll
    for (int ct = 0; ct < 4; ct++) {
#pragma unroll
        for (int r = 0; r < 4; r++) {
            int gr = mtile * 64 + w * 16 + (l >> 4) * 4 + r;
            int gc = ctile * 64 + ct * 16 + (l & 15);
            int b = gr / NN, n = gr % NN;
            int h = gc / DH, d = gc % DH;
            int bh = b * NH + h;
            q[(bh * NN + n) * DH + d]  = f2bf((acc[0][ct][r] + bq[gc]) * 0.125f);
            k[(bh * NN + n) * DH + d]  = f2bf(acc[1][ct][r] + bk[gc]);
            vT[(bh * DH + d) * NN + n] = f2bf(acc[2][ct][r] + bv[gc]);
        }
    }
}

// ---- flash attention: per block one (b,h,qtile of 64 rows); 4 waves x 16 rows ----
__global__ __launch_bounds__(256) void attn_k(
    const unsigned short* __restrict__ q, const unsigned short* __restrict__ k,
    const unsigned short* __restrict__ vT, unsigned short* __restrict__ z) {
    __shared__ unsigned short plds[4][16][64];
    int bh = blockIdx.x >> 5;
    int qt = blockIdx.x & 31;
    int b = bh / NH, h = bh % NH;
    int w = threadIdx.x >> 6, l = threadIdx.x & 63;
    const unsigned short* qp = q + (size_t)bh * NN * DH;
    const unsigned short* kp = k + (size_t)bh * NN * DH;
    const unsigned short* vp = vT + (size_t)bh * DH * NN;
    int qrow = qt * 64 + w * 16 + (l & 15);
    int klane = 8 * (l >> 4);

    v8s aq0 = *(const v8s*)(qp + qrow * DH + klane);
    v8s aq1 = *(const v8s*)(qp + qrow * DH + 32 + klane);

    v4f zero = {0.f, 0.f, 0.f, 0.f};
    float mrow[4], lsum[4];
    v4f o[4];
#pragma unroll
    for (int r = 0; r < 4; r++) { mrow[r] = -INFINITY; lsum[r] = 0.f; }
#pragma unroll
    for (int dt = 0; dt < 4; dt++) o[dt] = zero;

    for (int kv = 0; kv < NN; kv += 64) {
        v4f s[4];
#pragma unroll
        for (int ct = 0; ct < 4; ct++) {
            int krow = kv + ct * 16 + (l & 15);
            v8s b0 = *(const v8s*)(kp + krow * DH + klane);
            v8s b1 = *(const v8s*)(kp + krow * DH + 32 + klane);
            s[ct] = __builtin_amdgcn_mfma_f32_16x16x32_bf16(aq0, b0, zero, 0, 0, 0);
            s[ct] = __builtin_amdgcn_mfma_f32_16x16x32_bf16(aq1, b1, s[ct], 0, 0, 0);
        }
        float scl[4];
#pragma unroll
        for (int r = 0; r < 4; r++) {
            float vmax = fmaxf(fmaxf(s[0][r], s[1][r]), fmaxf(s[2][r], s[3][r]));
            vmax = fmaxf(vmax, __shfl_xor(vmax, 1));
            vmax = fmaxf(vmax, __shfl_xor(vmax, 2));
            vmax = fmaxf(vmax, __shfl_xor(vmax, 4));
            vmax = fmaxf(vmax, __shfl_xor(vmax, 8));
            float mn = fmaxf(mrow[r], vmax);
            float sc = __expf(mrow[r] - mn);
            float p0 = __expf(s[0][r] - mn);
            float p1 = __expf(s[1][r] - mn);
            float p2 = __expf(s[2][r] - mn);
            float p3 = __expf(s[3][r] - mn);
            float rs = p0 + p1 + p2 + p3;
            rs += __shfl_xor(rs, 1);
            rs += __shfl_xor(rs, 2);
            rs += __shfl_xor(rs, 4);
            rs += __shfl_xor(rs, 8);
            lsum[r] = lsum[r] * sc + rs;
            mrow[r] = mn;
            scl[r] = sc;
            int prow = (l >> 4) * 4 + r;
            plds[w][prow][0 * 16 + (l & 15)] = f2bf(p0);
            plds[w][prow][1 * 16 + (l & 15)] = f2bf(p1);
            plds[w][prow][2 * 16 + (l & 15)] = f2bf(p2);
            plds[w][prow][3 * 16 + (l & 15)] = f2bf(p3);
        }
#pragma unroll
        for (int dt = 0; dt < 4; dt++)
#pragma unroll
            for (int r = 0; r < 4; r++) o[dt][r] *= scl[r];

        v8s pa0 = *(const v8s*)(&plds[w][l & 15][klane]);
        v8s pa1 = *(const v8s*)(&plds[w][l & 15][32 + klane]);
#pragma unroll
        for (int dt = 0; dt < 4; dt++) {
            int dcol = dt * 16 + (l & 15);
            v8s bv0 = *(const v8s*)(vp + dcol * NN + kv + klane);
            v8s bv1 = *(const v8s*)(vp + dcol * NN + kv + 32 + klane);
            o[dt] = __builtin_amdgcn_mfma_f32_16x16x32_bf16(pa0, bv0, o[dt], 0, 0, 0);
            o[dt] = __builtin_amdgcn_mfma_f32_16x16x32_bf16(pa1, bv1, o[dt], 0, 0, 0);
        }
    }

    float inv[4];
#pragma unroll
    for (int r = 0; r < 4; r++) inv[r] = 1.f / lsum[r];
#pragma unroll
    for (int dt = 0; dt < 4; dt++)
#pragma unroll
        for (int r = 0; r < 4; r++) {
            int rowi = (l >> 4) * 4 + r;
            int n = qt * 64 + w * 16 + rowi;
            int c = h * DH + dt * 16 + (l & 15);
            z[((size_t)(b * NN + n)) * DM + c] = f2bf(o[dt][r] * inv[r]);
        }
}

// ---- output projection: z[4096,768] @ wo + bo -> fp32 out ----
__global__ __launch_bounds__(256) void out_gemm_k(
    const unsigned short* __restrict__ zb, const unsigned short* __restrict__ woT,
    const float* __restrict__ bo, float* __restrict__ out) {
    int ctile = blockIdx.x;
    int mtile = blockIdx.y;
    int w = threadIdx.x >> 6, l = threadIdx.x & 63;
    int row = mtile * 64 + w * 16 + (l & 15);
    int klane = 8 * (l >> 4);
    v4f zero = {0.f, 0.f, 0.f, 0.f};
    v4f acc[4];
#pragma unroll
    for (int ct = 0; ct < 4; ct++) acc[ct] = zero;

#pragma unroll 4
    for (int k0 = 0; k0 < 768; k0 += 32) {
        v8s a = *(const v8s*)(zb + row * 768 + k0 + klane);
#pragma unroll
        for (int ct = 0; ct < 4; ct++) {
            int col = ctile * 64 + ct * 16 + (l & 15);
            v8s bfr = *(const v8s*)(woT + col * 768 + k0 + klane);
            acc[ct] = __builtin_amdgcn_mfma_f32_16x16x32_bf16(a, bfr, acc[ct], 0, 0, 0);
        }
    }
#pragma unroll
    for (int ct = 0; ct < 4; ct++)
#pragma unroll
        for (int r = 0; r < 4; r++) {
            int gr = mtile * 64 + w * 16 + (l >> 4) * 4 + r;
            int gc = ctile * 64 + ct * 16 + (l & 15);
            out[gr * 768 + gc] = acc[ct][r] + bo[gc];
        }
}

extern "C" void kernel_launch(void* const* d_in, const int* in_sizes, int n_in,
                              void* d_out, int out_size, void* d_ws, size_t ws_size,
                              hipStream_t stream) {
    const float* x  = (const float*)d_in[0];
    const float* wq = (const float*)d_in[1];
    const float* bq = (const float*)d_in[2];
    const float* wk = (const float*)d_in[3];
    const float* bk = (const float*)d_in[4];
    const float* wv = (const float*)d_in[5];
    const float* bv = (const float*)d_in[6];
    const float* wo = (const float*)d_in[7];
    const float* bo = (const float*)d_in[8];
    float* out = (float*)d_out;

    const int NX = BB * NN * DM;       // 3,145,728
    const int NW = 768 * 768;          // 589,824

    unsigned short* wsp = (unsigned short*)d_ws;
    unsigned short* xb  = wsp;
    unsigned short* wqT = xb + NX;
    unsigned short* wkT = wqT + NW;
    unsigned short* wvT = wkT + NW;
    unsigned short* woT = wvT + NW;
    unsigned short* qb  = woT + NW;
    unsigned short* kb  = qb + NX;
    unsigned short* vTb = kb + NX;
    unsigned short* zb  = vTb + NX;

    cast_x_k<<<NX / (256 * 4), 256, 0, stream>>>(x, xb, NX);
    cast_wT_k<<<dim3(NW / 256, 4), 256, 0, stream>>>(wq, wk, wv, wo, wqT, wkT, wvT, woT);
    qkv_gemm_k<<<dim3(12, 64), 256, 0, stream>>>(xb, wqT, wkT, wvT, bq, bk, bv, qb, kb, vTb);
    attn_k<<<BB * NH * (NN / 64), 256, 0, stream>>>(qb, kb, vTb, zb);
    out_gemm_k<<<dim3(12, 64), 256, 0, stream>>>(zb, woT, bo, out);
}

// Round 2
// 306.268 us; speedup vs baseline: 1.1312x; 1.1312x over previous
//
#include <hip/hip_runtime.h>
#include <hip/hip_bf16.h>
#include <math.h>

#define NH 12
#define DH 64
#define BB 2
#define NN 2048
#define DM 768

typedef short v8s __attribute__((ext_vector_type(8)));
typedef float v4f __attribute__((ext_vector_type(4)));

__device__ __forceinline__ unsigned short f2bf(float f) {
    union { float f; unsigned u; } x; x.f = f;
    unsigned r = x.u + 0x7fffu + ((x.u >> 16) & 1u);
    return (unsigned short)(r >> 16);
}

// ---- cast x (fp32 -> bf16, layout-preserving) ----
__global__ __launch_bounds__(256) void cast_x_k(const float* __restrict__ in,
                                                unsigned short* __restrict__ out, int n) {
    int i = (blockIdx.x * 256 + threadIdx.x) * 4;
    if (i >= n) return;
    float4 v = *(const float4*)(in + i);
    ushort4 o;
    o.x = f2bf(v.x); o.y = f2bf(v.y); o.z = f2bf(v.z); o.w = f2bf(v.w);
    *(ushort4*)(out + i) = o;
}

// ---- cast + transpose weights via LDS tile (64x64): out[c][k] = in[k][c] ----
__global__ __launch_bounds__(256) void cast_wT_k(const float* __restrict__ w0, const float* __restrict__ w1,
                                                 const float* __restrict__ w2, const float* __restrict__ w3,
                                                 unsigned short* __restrict__ o0, unsigned short* __restrict__ o1,
                                                 unsigned short* __restrict__ o2, unsigned short* __restrict__ o3) {
    __shared__ unsigned short t[64][65];
    const float* in; unsigned short* out;
    switch (blockIdx.y) {
        case 0: in = w0; out = o0; break;
        case 1: in = w1; out = o1; break;
        case 2: in = w2; out = o2; break;
        default: in = w3; out = o3; break;
    }
    int kt = blockIdx.x / 12, ct = blockIdx.x % 12;
    int rr = threadIdx.x >> 4, cc = threadIdx.x & 15;
#pragma unroll
    for (int it = 0; it < 4; it++) {
        int row = kt * 64 + it * 16 + rr;       // global k (coalesced fp32 read)
        int col = ct * 64 + cc * 4;             // global c
        float4 v = *(const float4*)(in + row * 768 + col);
        t[it * 16 + rr][cc * 4 + 0] = f2bf(v.x);
        t[it * 16 + rr][cc * 4 + 1] = f2bf(v.y);
        t[it * 16 + rr][cc * 4 + 2] = f2bf(v.z);
        t[it * 16 + rr][cc * 4 + 3] = f2bf(v.w);
    }
    __syncthreads();
#pragma unroll
    for (int it = 0; it < 4; it++) {
        int c_l = it * 16 + rr;                  // local c
        int k_l = cc * 4;                        // local k
        ushort4 o;
        o.x = t[k_l + 0][c_l];
        o.y = t[k_l + 1][c_l];
        o.z = t[k_l + 2][c_l];
        o.w = t[k_l + 3][c_l];
        *(ushort4*)(out + (ct * 64 + c_l) * 768 + kt * 64 + k_l) = o;  // coalesced bf16 write
    }
}

// ---- fused QKV projection: [4096,768] @ {wq,wk,wv} + bias; 32 rows/wave ----
// q stored [B,H,N,D] bf16 with 0.125*log2(e) folded; k [B,H,N,D]; v transposed [B,H,D,N]
__global__ __launch_bounds__(256) void qkv_gemm_k(
    const unsigned short* __restrict__ xb,
    const unsigned short* __restrict__ wqT, const unsigned short* __restrict__ wkT,
    const unsigned short* __restrict__ wvT,
    const float* __restrict__ bq, const float* __restrict__ bk, const float* __restrict__ bv,
    unsigned short* __restrict__ q, unsigned short* __restrict__ k, unsigned short* __restrict__ vT) {
    int ctile = blockIdx.x;            // 12 tiles of 64 cols
    int mtile = blockIdx.y;            // 32 tiles of 128 rows
    int w = threadIdx.x >> 6, l = threadIdx.x & 63;
    int q16 = l & 15, g = l >> 4;
    int row0 = mtile * 128 + w * 32 + q16;
    int kl = 8 * g;
    v4f zero = {0.f, 0.f, 0.f, 0.f};
    v4f acc[3][2][4];
#pragma unroll
    for (int m = 0; m < 3; m++)
#pragma unroll
        for (int rf = 0; rf < 2; rf++)
#pragma unroll
            for (int ct = 0; ct < 4; ct++) acc[m][rf][ct] = zero;

#pragma unroll 2
    for (int k0 = 0; k0 < 768; k0 += 32) {
        v8s a0 = *(const v8s*)(xb + row0 * 768 + k0 + kl);
        v8s a1 = *(const v8s*)(xb + (row0 + 16) * 768 + k0 + kl);
#pragma unroll
        for (int ct = 0; ct < 4; ct++) {
            int col = ctile * 64 + ct * 16 + q16;
            v8s b0 = *(const v8s*)(wqT + col * 768 + k0 + kl);
            v8s b1 = *(const v8s*)(wkT + col * 768 + k0 + kl);
            v8s b2 = *(const v8s*)(wvT + col * 768 + k0 + kl);
            acc[0][0][ct] = __builtin_amdgcn_mfma_f32_16x16x32_bf16(a0, b0, acc[0][0][ct], 0, 0, 0);
            acc[0][1][ct] = __builtin_amdgcn_mfma_f32_16x16x32_bf16(a1, b0, acc[0][1][ct], 0, 0, 0);
            acc[1][0][ct] = __builtin_amdgcn_mfma_f32_16x16x32_bf16(a0, b1, acc[1][0][ct], 0, 0, 0);
            acc[1][1][ct] = __builtin_amdgcn_mfma_f32_16x16x32_bf16(a1, b1, acc[1][1][ct], 0, 0, 0);
            acc[2][0][ct] = __builtin_amdgcn_mfma_f32_16x16x32_bf16(a0, b2, acc[2][0][ct], 0, 0, 0);
            acc[2][1][ct] = __builtin_amdgcn_mfma_f32_16x16x32_bf16(a1, b2, acc[2][1][ct], 0, 0, 0);
        }
    }

    const float QSCL = 0.125f * 1.44269504088896340736f;  // fold 1/sqrt(D) * log2(e)
#pragma unroll
    for (int rf = 0; rf < 2; rf++)
#pragma unroll
        for (int ct = 0; ct < 4; ct++)
#pragma unroll
            for (int r = 0; r < 4; r++) {
                int gr = mtile * 128 + w * 32 + rf * 16 + 4 * g + r;
                int gc = ctile * 64 + ct * 16 + q16;
                int b = gr / NN, n = gr % NN;
                int h = gc / DH, d = gc % DH;
                int bh = b * NH + h;
                q[(bh * NN + n) * DH + d]  = f2bf((acc[0][rf][ct][r] + bq[gc]) * QSCL);
                k[(bh * NN + n) * DH + d]  = f2bf(acc[1][rf][ct][r] + bk[gc]);
                vT[(bh * DH + d) * NN + n] = f2bf(acc[2][rf][ct][r] + bv[gc]);
            }
}

// ---- flash attention, swapped operands ----
// QK^T swapped: S^T = mfma(K, Q) -> lane (q = l&15) holds 16 P values -> in-lane softmax
// PV swapped:   O^T = mfma(V^T, P^T) -> rescale & 1/lsum stay lane-local
__global__ __launch_bounds__(256) void attn_k(
    const unsigned short* __restrict__ q, const unsigned short* __restrict__ k,
    const unsigned short* __restrict__ vT, unsigned short* __restrict__ z) {
    __shared__ unsigned short plds[4][16][72];   // [wave][q][k+pad]; pad=8 -> conflict-free
    int bh = blockIdx.x >> 5;
    int qt = blockIdx.x & 31;
    int b = bh / NH, h = bh % NH;
    int w = threadIdx.x >> 6, l = threadIdx.x & 63;
    int q16 = l & 15, g = l >> 4;
    const unsigned short* qp = q + (size_t)bh * NN * DH;
    const unsigned short* kp = k + (size_t)bh * NN * DH;
    const unsigned short* vp = vT + (size_t)bh * DH * NN;
    int qrow = qt * 64 + w * 16 + q16;

    // Q fragments (B-operand of swapped QK^T == row-major load of q-row l&15)
    v8s qf0 = *(const v8s*)(qp + qrow * DH + 8 * g);
    v8s qf1 = *(const v8s*)(qp + qrow * DH + 32 + 8 * g);

    v4f zero = {0.f, 0.f, 0.f, 0.f};
    float mrow = -INFINITY, lsum = 0.f;
    v4f o[4];
#pragma unroll
    for (int dt = 0; dt < 4; dt++) o[dt] = zero;

    for (int kv = 0; kv < NN; kv += 64) {
        v4f st[4];
#pragma unroll
        for (int ct = 0; ct < 4; ct++) {
            int krow = kv + ct * 16 + q16;
            v8s kf0 = *(const v8s*)(kp + krow * DH + 8 * g);
            v8s kf1 = *(const v8s*)(kp + krow * DH + 32 + 8 * g);
            st[ct] = __builtin_amdgcn_mfma_f32_16x16x32_bf16(kf0, qf0, zero, 0, 0, 0);
            st[ct] = __builtin_amdgcn_mfma_f32_16x16x32_bf16(kf1, qf1, st[ct], 0, 0, 0);
        }
        // in-lane max over this lane's 16 k-values (all belong to q = l&15)
        float vmax = fmaxf(fmaxf(fmaxf(st[0][0], st[0][1]), fmaxf(st[0][2], st[0][3])),
                           fmaxf(fmaxf(st[1][0], st[1][1]), fmaxf(st[1][2], st[1][3])));
        vmax = fmaxf(vmax, fmaxf(fmaxf(fmaxf(st[2][0], st[2][1]), fmaxf(st[2][2], st[2][3])),
                                 fmaxf(fmaxf(st[3][0], st[3][1]), fmaxf(st[3][2], st[3][3]))));
        vmax = fmaxf(vmax, __shfl_xor(vmax, 16));
        vmax = fmaxf(vmax, __shfl_xor(vmax, 32));
        float mn = fmaxf(mrow, vmax);
        float sc = exp2f(mrow - mn);
        float rs = 0.f;
#pragma unroll
        for (int ct = 0; ct < 4; ct++) {
            float p0 = exp2f(st[ct][0] - mn);
            float p1 = exp2f(st[ct][1] - mn);
            float p2 = exp2f(st[ct][2] - mn);
            float p3 = exp2f(st[ct][3] - mn);
            rs += (p0 + p1) + (p2 + p3);
            short4 pk;
            pk.x = (short)f2bf(p0); pk.y = (short)f2bf(p1);
            pk.z = (short)f2bf(p2); pk.w = (short)f2bf(p3);
            *(short4*)(&plds[w][q16][ct * 16 + 4 * g]) = pk;
        }
        rs += __shfl_xor(rs, 16);
        rs += __shfl_xor(rs, 32);
        lsum = lsum * sc + rs;
        mrow = mn;
#pragma unroll
        for (int dt = 0; dt < 4; dt++)
#pragma unroll
            for (int r = 0; r < 4; r++) o[dt][r] *= sc;

        // P^T fragments (B-operand of swapped PV): contiguous 16B reads
        v8s pf0 = *(const v8s*)(&plds[w][q16][8 * g]);
        v8s pf1 = *(const v8s*)(&plds[w][q16][32 + 8 * g]);
#pragma unroll
        for (int dt = 0; dt < 4; dt++) {
            int dcol = dt * 16 + q16;
            v8s vf0 = *(const v8s*)(vp + dcol * NN + kv + 8 * g);
            v8s vf1 = *(const v8s*)(vp + dcol * NN + kv + 32 + 8 * g);
            o[dt] = __builtin_amdgcn_mfma_f32_16x16x32_bf16(vf0, pf0, o[dt], 0, 0, 0);
            o[dt] = __builtin_amdgcn_mfma_f32_16x16x32_bf16(vf1, pf1, o[dt], 0, 0, 0);
        }
    }

    float inv = 1.f / lsum;
    int n = qt * 64 + w * 16 + q16;
#pragma unroll
    for (int dt = 0; dt < 4; dt++) {
        short4 s4;
        s4.x = (short)f2bf(o[dt][0] * inv);
        s4.y = (short)f2bf(o[dt][1] * inv);
        s4.z = (short)f2bf(o[dt][2] * inv);
        s4.w = (short)f2bf(o[dt][3] * inv);
        *(short4*)(&z[((size_t)(b * NN + n)) * DM + h * DH + dt * 16 + 4 * g]) = s4;
    }
}

// ---- output projection: z[4096,768] @ wo + bo -> fp32 out; 32 rows/wave ----
__global__ __launch_bounds__(256) void out_gemm_k(
    const unsigned short* __restrict__ zb, const unsigned short* __restrict__ woT,
    const float* __restrict__ bo, float* __restrict__ out) {
    int ctile = blockIdx.x;
    int mtile = blockIdx.y;
    int w = threadIdx.x >> 6, l = threadIdx.x & 63;
    int q16 = l & 15, g = l >> 4;
    int row0 = mtile * 128 + w * 32 + q16;
    int kl = 8 * g;
    v4f zero = {0.f, 0.f, 0.f, 0.f};
    v4f acc[2][4];
#pragma unroll
    for (int rf = 0; rf < 2; rf++)
#pragma unroll
        for (int ct = 0; ct < 4; ct++) acc[rf][ct] = zero;

#pragma unroll 2
    for (int k0 = 0; k0 < 768; k0 += 32) {
        v8s a0 = *(const v8s*)(zb + row0 * 768 + k0 + kl);
        v8s a1 = *(const v8s*)(zb + (row0 + 16) * 768 + k0 + kl);
#pragma unroll
        for (int ct = 0; ct < 4; ct++) {
            int col = ctile * 64 + ct * 16 + q16;
            v8s bfr = *(const v8s*)(woT + col * 768 + k0 + kl);
            acc[0][ct] = __builtin_amdgcn_mfma_f32_16x16x32_bf16(a0, bfr, acc[0][ct], 0, 0, 0);
            acc[1][ct] = __builtin_amdgcn_mfma_f32_16x16x32_bf16(a1, bfr, acc[1][ct], 0, 0, 0);
        }
    }
#pragma unroll
    for (int rf = 0; rf < 2; rf++)
#pragma unroll
        for (int ct = 0; ct < 4; ct++)
#pragma unroll
            for (int r = 0; r < 4; r++) {
                int gr = mtile * 128 + w * 32 + rf * 16 + 4 * g + r;
                int gc = ctile * 64 + ct * 16 + q16;
                out[gr * 768 + gc] = acc[rf][ct][r] + bo[gc];
            }
}

extern "C" void kernel_launch(void* const* d_in, const int* in_sizes, int n_in,
                              void* d_out, int out_size, void* d_ws, size_t ws_size,
                              hipStream_t stream) {
    const float* x  = (const float*)d_in[0];
    const float* wq = (const float*)d_in[1];
    const float* bq = (const float*)d_in[2];
    const float* wk = (const float*)d_in[3];
    const float* bk = (const float*)d_in[4];
    const float* wv = (const float*)d_in[5];
    const float* bv = (const float*)d_in[6];
    const float* wo = (const float*)d_in[7];
    const float* bo = (const float*)d_in[8];
    float* out = (float*)d_out;

    const int NX = BB * NN * DM;       // 3,145,728
    const int NW = 768 * 768;          // 589,824

    unsigned short* wsp = (unsigned short*)d_ws;
    unsigned short* xb  = wsp;
    unsigned short* wqT = xb + NX;
    unsigned short* wkT = wqT + NW;
    unsigned short* wvT = wkT + NW;
    unsigned short* woT = wvT + NW;
    unsigned short* qb  = woT + NW;
    unsigned short* kb  = qb + NX;
    unsigned short* vTb = kb + NX;
    unsigned short* zb  = vTb + NX;

    cast_x_k<<<NX / (256 * 4), 256, 0, stream>>>(x, xb, NX);
    cast_wT_k<<<dim3(144, 4), 256, 0, stream>>>(wq, wk, wv, wo, wqT, wkT, wvT, woT);
    qkv_gemm_k<<<dim3(12, 32), 256, 0, stream>>>(xb, wqT, wkT, wvT, bq, bk, bv, qb, kb, vTb);
    attn_k<<<BB * NH * (NN / 64), 256, 0, stream>>>(qb, kb, vTb, zb);
    out_gemm_k<<<dim3(12, 32), 256, 0, stream>>>(zb, woT, bo, out);
}

// Round 3
// 202.492 us; speedup vs baseline: 1.7109x; 1.5125x over previous
//
#include <hip/hip_runtime.h>
#include <hip/hip_bf16.h>
#include <math.h>

#define NH 12
#define DH 64
#define BB 2
#define NN 2048
#define DM 768

typedef short v8s __attribute__((ext_vector_type(8)));
typedef float v4f __attribute__((ext_vector_type(4)));

__device__ __forceinline__ unsigned short f2bf(float f) {
    union { float f; unsigned u; } x; x.f = f;
    unsigned r = x.u + 0x7fffu + ((x.u >> 16) & 1u);
    return (unsigned short)(r >> 16);
}

__device__ __forceinline__ void glds16(const void* g, void* l) {
    __builtin_amdgcn_global_load_lds((const __attribute__((address_space(1))) void*)g,
                                     (__attribute__((address_space(3))) void*)l, 16, 0, 0);
}

// ---- cast x (fp32 -> bf16, layout-preserving) ----
__global__ __launch_bounds__(256) void cast_x_k(const float* __restrict__ in,
                                                unsigned short* __restrict__ out, int n) {
    int i = (blockIdx.x * 256 + threadIdx.x) * 4;
    if (i >= n) return;
    float4 v = *(const float4*)(in + i);
    ushort4 o;
    o.x = f2bf(v.x); o.y = f2bf(v.y); o.z = f2bf(v.z); o.w = f2bf(v.w);
    *(ushort4*)(out + i) = o;
}

// ---- cast + transpose weights via LDS tile (64x64): out[c][k] = in[k][c] ----
__global__ __launch_bounds__(256) void cast_wT_k(const float* __restrict__ w0, const float* __restrict__ w1,
                                                 const float* __restrict__ w2, const float* __restrict__ w3,
                                                 unsigned short* __restrict__ o0, unsigned short* __restrict__ o1,
                                                 unsigned short* __restrict__ o2, unsigned short* __restrict__ o3) {
    __shared__ unsigned short t[64][65];
    const float* in; unsigned short* out;
    switch (blockIdx.y) {
        case 0: in = w0; out = o0; break;
        case 1: in = w1; out = o1; break;
        case 2: in = w2; out = o2; break;
        default: in = w3; out = o3; break;
    }
    int kt = blockIdx.x / 12, ct = blockIdx.x % 12;
    int rr = threadIdx.x >> 4, cc = threadIdx.x & 15;
#pragma unroll
    for (int it = 0; it < 4; it++) {
        int row = kt * 64 + it * 16 + rr;
        int col = ct * 64 + cc * 4;
        float4 v = *(const float4*)(in + row * 768 + col);
        t[it * 16 + rr][cc * 4 + 0] = f2bf(v.x);
        t[it * 16 + rr][cc * 4 + 1] = f2bf(v.y);
        t[it * 16 + rr][cc * 4 + 2] = f2bf(v.z);
        t[it * 16 + rr][cc * 4 + 3] = f2bf(v.w);
    }
    __syncthreads();
#pragma unroll
    for (int it = 0; it < 4; it++) {
        int c_l = it * 16 + rr;
        int k_l = cc * 4;
        ushort4 o;
        o.x = t[k_l + 0][c_l];
        o.y = t[k_l + 1][c_l];
        o.z = t[k_l + 2][c_l];
        o.w = t[k_l + 3][c_l];
        *(ushort4*)(out + (ct * 64 + c_l) * 768 + kt * 64 + k_l) = o;
    }
}

// ---- fused QKV projection: [4096,768] @ {wq,wk,wv} + bias; 32 rows/wave ----
__global__ __launch_bounds__(256) void qkv_gemm_k(
    const unsigned short* __restrict__ xb,
    const unsigned short* __restrict__ wqT, const unsigned short* __restrict__ wkT,
    const unsigned short* __restrict__ wvT,
    const float* __restrict__ bq, const float* __restrict__ bk, const float* __restrict__ bv,
    unsigned short* __restrict__ q, unsigned short* __restrict__ k, unsigned short* __restrict__ vT) {
    int ctile = blockIdx.x;
    int mtile = blockIdx.y;
    int w = threadIdx.x >> 6, l = threadIdx.x & 63;
    int q16 = l & 15, g = l >> 4;
    int row0 = mtile * 128 + w * 32 + q16;
    int kl = 8 * g;
    v4f zero = {0.f, 0.f, 0.f, 0.f};
    v4f acc[3][2][4];
#pragma unroll
    for (int m = 0; m < 3; m++)
#pragma unroll
        for (int rf = 0; rf < 2; rf++)
#pragma unroll
            for (int ct = 0; ct < 4; ct++) acc[m][rf][ct] = zero;

#pragma unroll 2
    for (int k0 = 0; k0 < 768; k0 += 32) {
        v8s a0 = *(const v8s*)(xb + row0 * 768 + k0 + kl);
        v8s a1 = *(const v8s*)(xb + (row0 + 16) * 768 + k0 + kl);
#pragma unroll
        for (int ct = 0; ct < 4; ct++) {
            int col = ctile * 64 + ct * 16 + q16;
            v8s b0 = *(const v8s*)(wqT + col * 768 + k0 + kl);
            v8s b1 = *(const v8s*)(wkT + col * 768 + k0 + kl);
            v8s b2 = *(const v8s*)(wvT + col * 768 + k0 + kl);
            acc[0][0][ct] = __builtin_amdgcn_mfma_f32_16x16x32_bf16(a0, b0, acc[0][0][ct], 0, 0, 0);
            acc[0][1][ct] = __builtin_amdgcn_mfma_f32_16x16x32_bf16(a1, b0, acc[0][1][ct], 0, 0, 0);
            acc[1][0][ct] = __builtin_amdgcn_mfma_f32_16x16x32_bf16(a0, b1, acc[1][0][ct], 0, 0, 0);
            acc[1][1][ct] = __builtin_amdgcn_mfma_f32_16x16x32_bf16(a1, b1, acc[1][1][ct], 0, 0, 0);
            acc[2][0][ct] = __builtin_amdgcn_mfma_f32_16x16x32_bf16(a0, b2, acc[2][0][ct], 0, 0, 0);
            acc[2][1][ct] = __builtin_amdgcn_mfma_f32_16x16x32_bf16(a1, b2, acc[2][1][ct], 0, 0, 0);
        }
    }

    const float QSCL = 0.125f * 1.44269504088896340736f;
#pragma unroll
    for (int rf = 0; rf < 2; rf++)
#pragma unroll
        for (int ct = 0; ct < 4; ct++)
#pragma unroll
            for (int r = 0; r < 4; r++) {
                int gr = mtile * 128 + w * 32 + rf * 16 + 4 * g + r;
                int gc = ctile * 64 + ct * 16 + q16;
                int b = gr / NN, n = gr % NN;
                int h = gc / DH, d = gc % DH;
                int bh = b * NH + h;
                q[(bh * NN + n) * DH + d]  = f2bf((acc[0][rf][ct][r] + bq[gc]) * QSCL);
                k[(bh * NN + n) * DH + d]  = f2bf(acc[1][rf][ct][r] + bk[gc]);
                vT[(bh * DH + d) * NN + n] = f2bf(acc[2][rf][ct][r] + bv[gc]);
            }
}

// ---- flash attention: LDS-staged K/V tiles (double-buffered, swizzled), swapped-operand MFMA ----
__global__ __launch_bounds__(256) void attn_k(
    const unsigned short* __restrict__ q, const unsigned short* __restrict__ k,
    const unsigned short* __restrict__ vT, unsigned short* __restrict__ z) {
    __shared__ unsigned short Kbuf[2][64 * 64];   // [buf][row*64+col], XOR-swizzled contents
    __shared__ unsigned short Vbuf[2][64 * 64];
    __shared__ unsigned short plds[4][16][72];

    int bh = blockIdx.x % 24;                     // XCD-local: all 32 q-blocks of a head on one XCD
    int qt = blockIdx.x / 24;
    int b = bh / NH, h = bh % NH;
    int w = threadIdx.x >> 6, l = threadIdx.x & 63;
    int q16 = l & 15, g = l >> 4;
    const unsigned short* qp = q + (size_t)bh * NN * DH;
    const unsigned short* kp = k + (size_t)bh * NN * DH;
    const unsigned short* vp = vT + (size_t)bh * DH * NN;
    int qrow = qt * 64 + w * 16 + q16;

    v8s qf0 = *(const v8s*)(qp + qrow * DH + 8 * g);
    v8s qf1 = *(const v8s*)(qp + qrow * DH + 32 + 8 * g);

    // staging geometry: linear LDS dest (wave-uniform base + lane*16), pre-swizzled global source
    int sY = w * 2048 + l * 16;                   // byte offset of this lane's first 16B slot
    int srow0 = sY >> 7;                          // tile row for i=0 (i=1: +8)
    int ss = (sY >> 4) & 7;                       // 16B slot within row

    auto stage = [&](int t, int buf) {
        int kv = t * 64;
#pragma unroll
        for (int i = 0; i < 2; ++i) {
            int row = srow0 + i * 8;
            int c16 = ss ^ (row & 7);
            char* kdst = (char*)&Kbuf[buf][0] + w * 2048 + i * 1024;
            char* vdst = (char*)&Vbuf[buf][0] + w * 2048 + i * 1024;
            glds16(kp + (kv + row) * DH + (c16 << 3), kdst);
            glds16(vp + row * NN + kv + (c16 << 3), vdst);
        }
    };

    v4f zero = {0.f, 0.f, 0.f, 0.f};
    float mrow = -INFINITY, lsum = 0.f;
    v4f o[4];
#pragma unroll
    for (int dt = 0; dt < 4; dt++) o[dt] = zero;

    stage(0, 0);
    __syncthreads();

    for (int t = 0; t < NN / 64; ++t) {
        int cur = t & 1;
        if (t + 1 < NN / 64) stage(t + 1, cur ^ 1);

        const char* kb = (const char*)&Kbuf[cur][0];
        const char* vb = (const char*)&Vbuf[cur][0];

        v4f st[4];
#pragma unroll
        for (int ct = 0; ct < 4; ct++) {
            int krow = ct * 16 + q16;
            v8s kf0 = *(const v8s*)(kb + krow * 128 + ((g ^ (krow & 7)) << 4));
            v8s kf1 = *(const v8s*)(kb + krow * 128 + (((4 + g) ^ (krow & 7)) << 4));
            st[ct] = __builtin_amdgcn_mfma_f32_16x16x32_bf16(kf0, qf0, zero, 0, 0, 0);
            st[ct] = __builtin_amdgcn_mfma_f32_16x16x32_bf16(kf1, qf1, st[ct], 0, 0, 0);
        }

        float vmax = fmaxf(fmaxf(fmaxf(st[0][0], st[0][1]), fmaxf(st[0][2], st[0][3])),
                           fmaxf(fmaxf(st[1][0], st[1][1]), fmaxf(st[1][2], st[1][3])));
        vmax = fmaxf(vmax, fmaxf(fmaxf(fmaxf(st[2][0], st[2][1]), fmaxf(st[2][2], st[2][3])),
                                 fmaxf(fmaxf(st[3][0], st[3][1]), fmaxf(st[3][2], st[3][3]))));
        vmax = fmaxf(vmax, __shfl_xor(vmax, 16));
        vmax = fmaxf(vmax, __shfl_xor(vmax, 32));
        float mn = fmaxf(mrow, vmax);
        float sc = exp2f(mrow - mn);
        float rs = 0.f;
#pragma unroll
        for (int ct = 0; ct < 4; ct++) {
            float p0 = exp2f(st[ct][0] - mn);
            float p1 = exp2f(st[ct][1] - mn);
            float p2 = exp2f(st[ct][2] - mn);
            float p3 = exp2f(st[ct][3] - mn);
            rs += (p0 + p1) + (p2 + p3);
            short4 pk;
            pk.x = (short)f2bf(p0); pk.y = (short)f2bf(p1);
            pk.z = (short)f2bf(p2); pk.w = (short)f2bf(p3);
            *(short4*)(&plds[w][q16][ct * 16 + 4 * g]) = pk;
        }
        rs += __shfl_xor(rs, 16);
        rs += __shfl_xor(rs, 32);
        lsum = lsum * sc + rs;
        mrow = mn;
#pragma unroll
        for (int dt = 0; dt < 4; dt++)
#pragma unroll
            for (int r = 0; r < 4; r++) o[dt][r] *= sc;

        v8s pf0 = *(const v8s*)(&plds[w][q16][8 * g]);
        v8s pf1 = *(const v8s*)(&plds[w][q16][32 + 8 * g]);
#pragma unroll
        for (int dt = 0; dt < 4; dt++) {
            int dcol = dt * 16 + q16;
            v8s vf0 = *(const v8s*)(vb + dcol * 128 + ((g ^ (dcol & 7)) << 4));
            v8s vf1 = *(const v8s*)(vb + dcol * 128 + (((4 + g) ^ (dcol & 7)) << 4));
            o[dt] = __builtin_amdgcn_mfma_f32_16x16x32_bf16(vf0, pf0, o[dt], 0, 0, 0);
            o[dt] = __builtin_amdgcn_mfma_f32_16x16x32_bf16(vf1, pf1, o[dt], 0, 0, 0);
        }
        __syncthreads();
    }

    float inv = 1.f / lsum;
    int n = qt * 64 + w * 16 + q16;
#pragma unroll
    for (int dt = 0; dt < 4; dt++) {
        short4 s4;
        s4.x = (short)f2bf(o[dt][0] * inv);
        s4.y = (short)f2bf(o[dt][1] * inv);
        s4.z = (short)f2bf(o[dt][2] * inv);
        s4.w = (short)f2bf(o[dt][3] * inv);
        *(short4*)(&z[((size_t)(b * NN + n)) * DM + h * DH + dt * 16 + 4 * g]) = s4;
    }
}

// ---- output projection: z[4096,768] @ wo + bo -> fp32 out; 32 rows/wave ----
__global__ __launch_bounds__(256) void out_gemm_k(
    const unsigned short* __restrict__ zb, const unsigned short* __restrict__ woT,
    const float* __restrict__ bo, float* __restrict__ out) {
    int ctile = blockIdx.x;
    int mtile = blockIdx.y;
    int w = threadIdx.x >> 6, l = threadIdx.x & 63;
    int q16 = l & 15, g = l >> 4;
    int row0 = mtile * 128 + w * 32 + q16;
    int kl = 8 * g;
    v4f zero = {0.f, 0.f, 0.f, 0.f};
    v4f acc[2][4];
#pragma unroll
    for (int rf = 0; rf < 2; rf++)
#pragma unroll
        for (int ct = 0; ct < 4; ct++) acc[rf][ct] = zero;

#pragma unroll 2
    for (int k0 = 0; k0 < 768; k0 += 32) {
        v8s a0 = *(const v8s*)(zb + row0 * 768 + k0 + kl);
        v8s a1 = *(const v8s*)(zb + (row0 + 16) * 768 + k0 + kl);
#pragma unroll
        for (int ct = 0; ct < 4; ct++) {
            int col = ctile * 64 + ct * 16 + q16;
            v8s bfr = *(const v8s*)(woT + col * 768 + k0 + kl);
            acc[0][ct] = __builtin_amdgcn_mfma_f32_16x16x32_bf16(a0, bfr, acc[0][ct], 0, 0, 0);
            acc[1][ct] = __builtin_amdgcn_mfma_f32_16x16x32_bf16(a1, bfr, acc[1][ct], 0, 0, 0);
        }
    }
#pragma unroll
    for (int rf = 0; rf < 2; rf++)
#pragma unroll
        for (int ct = 0; ct < 4; ct++)
#pragma unroll
            for (int r = 0; r < 4; r++) {
                int gr = mtile * 128 + w * 32 + rf * 16 + 4 * g + r;
                int gc = ctile * 64 + ct * 16 + q16;
                out[gr * 768 + gc] = acc[rf][ct][r] + bo[gc];
            }
}

extern "C" void kernel_launch(void* const* d_in, const int* in_sizes, int n_in,
                              void* d_out, int out_size, void* d_ws, size_t ws_size,
                              hipStream_t stream) {
    const float* x  = (const float*)d_in[0];
    const float* wq = (const float*)d_in[1];
    const float* bq = (const float*)d_in[2];
    const float* wk = (const float*)d_in[3];
    const float* bk = (const float*)d_in[4];
    const float* wv = (const float*)d_in[5];
    const float* bv = (const float*)d_in[6];
    const float* wo = (const float*)d_in[7];
    const float* bo = (const float*)d_in[8];
    float* out = (float*)d_out;

    const int NX = BB * NN * DM;
    const int NW = 768 * 768;

    unsigned short* wsp = (unsigned short*)d_ws;
    unsigned short* xb  = wsp;
    unsigned short* wqT = xb + NX;
    unsigned short* wkT = wqT + NW;
    unsigned short* wvT = wkT + NW;
    unsigned short* woT = wvT + NW;
    unsigned short* qb  = woT + NW;
    unsigned short* kb  = qb + NX;
    unsigned short* vTb = kb + NX;
    unsigned short* zb  = vTb + NX;

    cast_x_k<<<NX / (256 * 4), 256, 0, stream>>>(x, xb, NX);
    cast_wT_k<<<dim3(144, 4), 256, 0, stream>>>(wq, wk, wv, wo, wqT, wkT, wvT, woT);
    qkv_gemm_k<<<dim3(12, 32), 256, 0, stream>>>(xb, wqT, wkT, wvT, bq, bk, bv, qb, kb, vTb);
    attn_k<<<BB * NH * (NN / 64), 256, 0, stream>>>(qb, kb, vTb, zb);
    out_gemm_k<<<dim3(12, 32), 256, 0, stream>>>(zb, woT, bo, out);
}

// Round 4
// 146.260 us; speedup vs baseline: 2.3687x; 1.3845x over previous
//
#include <hip/hip_runtime.h>
#include <hip/hip_bf16.h>
#include <math.h>

#define NH 12
#define DH 64
#define BB 2
#define NN 2048
#define DM 768

typedef short v8s __attribute__((ext_vector_type(8)));
typedef float v4f __attribute__((ext_vector_type(4)));

__device__ __forceinline__ unsigned short f2bf(float f) {
    union { float f; unsigned u; } x; x.f = f;
    unsigned r = x.u + 0x7fffu + ((x.u >> 16) & 1u);
    return (unsigned short)(r >> 16);
}

__device__ __forceinline__ void glds16(const void* g, void* l) {
    __builtin_amdgcn_global_load_lds((const __attribute__((address_space(1))) void*)g,
                                     (__attribute__((address_space(3))) void*)l, 16, 0, 0);
}

// ---- cast x (fp32 -> bf16, layout-preserving) ----
__global__ __launch_bounds__(256) void cast_x_k(const float* __restrict__ in,
                                                unsigned short* __restrict__ out, int n) {
    int i = (blockIdx.x * 256 + threadIdx.x) * 4;
    if (i >= n) return;
    float4 v = *(const float4*)(in + i);
    ushort4 o;
    o.x = f2bf(v.x); o.y = f2bf(v.y); o.z = f2bf(v.z); o.w = f2bf(v.w);
    *(ushort4*)(out + i) = o;
}

// ---- cast + transpose weights via LDS tile (64x64): out[c][k] = in[k][c] ----
__global__ __launch_bounds__(256) void cast_wT_k(const float* __restrict__ w0, const float* __restrict__ w1,
                                                 const float* __restrict__ w2, const float* __restrict__ w3,
                                                 unsigned short* __restrict__ o0, unsigned short* __restrict__ o1,
                                                 unsigned short* __restrict__ o2, unsigned short* __restrict__ o3) {
    __shared__ unsigned short t[64][65];
    const float* in; unsigned short* out;
    switch (blockIdx.y) {
        case 0: in = w0; out = o0; break;
        case 1: in = w1; out = o1; break;
        case 2: in = w2; out = o2; break;
        default: in = w3; out = o3; break;
    }
    int kt = blockIdx.x / 12, ct = blockIdx.x % 12;
    int rr = threadIdx.x >> 4, cc = threadIdx.x & 15;
#pragma unroll
    for (int it = 0; it < 4; it++) {
        int row = kt * 64 + it * 16 + rr;
        int col = ct * 64 + cc * 4;
        float4 v = *(const float4*)(in + row * 768 + col);
        t[it * 16 + rr][cc * 4 + 0] = f2bf(v.x);
        t[it * 16 + rr][cc * 4 + 1] = f2bf(v.y);
        t[it * 16 + rr][cc * 4 + 2] = f2bf(v.z);
        t[it * 16 + rr][cc * 4 + 3] = f2bf(v.w);
    }
    __syncthreads();
#pragma unroll
    for (int it = 0; it < 4; it++) {
        int c_l = it * 16 + rr;
        int k_l = cc * 4;
        ushort4 o;
        o.x = t[k_l + 0][c_l];
        o.y = t[k_l + 1][c_l];
        o.z = t[k_l + 2][c_l];
        o.w = t[k_l + 3][c_l];
        *(ushort4*)(out + (ct * 64 + c_l) * 768 + kt * 64 + k_l) = o;
    }
}

// ---- fused QKV projection as one GEMM over N=2304 (concat wq|wk|wv cols) ----
// 128x128 tile, 4 waves (2x2 of 64x64), BK=32, double-buffered LDS, glds16 staging.
// LDS tile rows are 64B (32 bf16); swizzle: slot' = slot ^ ((row>>1)&3).
__global__ __launch_bounds__(256) void qkv_gemm_k(
    const unsigned short* __restrict__ xb,
    const unsigned short* __restrict__ wqT, const unsigned short* __restrict__ wkT,
    const unsigned short* __restrict__ wvT,
    const float* __restrict__ bq, const float* __restrict__ bk, const float* __restrict__ bv,
    unsigned short* __restrict__ q, unsigned short* __restrict__ k, unsigned short* __restrict__ vT) {
    __shared__ unsigned short Abuf[2][128 * 32];   // 8 KB each
    __shared__ unsigned short Bbuf[2][128 * 32];

    int ctile = blockIdx.x;              // 0..17
    int mtile = blockIdx.y;              // 0..31
    int mat = ctile / 6;                 // 0=q 1=k 2=v
    int col0 = (ctile % 6) * 128;
    const unsigned short* Bsrc = (mat == 0) ? wqT : ((mat == 1) ? wkT : wvT);
    const float* bias = (mat == 0) ? bq : ((mat == 1) ? bk : bv);

    int tid = threadIdx.x;
    int w = tid >> 6, l = tid & 63;
    int q16 = l & 15, g = l >> 4;
    int wr = w >> 1, wc = w & 1;

    // staging geometry: thread tid stages 16B at linear LDS offset i*4096 + tid*16
    int srow0 = tid >> 2;                // row for i=0 (i=1: +64)
    int ss = tid & 3;                    // slot within 64B row

    auto stage = [&](int tt, int buf) {
        int k0 = tt * 32;
#pragma unroll
        for (int i = 0; i < 2; ++i) {
            int row = srow0 + i * 64;
            int c16 = ss ^ ((row >> 1) & 3);
            glds16(xb + (mtile * 128 + row) * 768 + k0 + (c16 << 3),
                   (char*)&Abuf[buf][0] + i * 4096 + tid * 16);
            glds16(Bsrc + (col0 + row) * 768 + k0 + (c16 << 3),
                   (char*)&Bbuf[buf][0] + i * 4096 + tid * 16);
        }
    };

    v4f zero = {0.f, 0.f, 0.f, 0.f};
    v4f acc[4][4];
#pragma unroll
    for (int i = 0; i < 4; i++)
#pragma unroll
        for (int j = 0; j < 4; j++) acc[i][j] = zero;

    stage(0, 0);
    __syncthreads();

    for (int tt = 0; tt < 24; ++tt) {
        int cur = tt & 1;
        if (tt + 1 < 24) stage(tt + 1, cur ^ 1);
        const char* Ab = (const char*)&Abuf[cur][0];
        const char* Bb = (const char*)&Bbuf[cur][0];
        v8s af[4], bf[4];
#pragma unroll
        for (int f = 0; f < 4; f++) {
            int arow = wr * 64 + f * 16 + q16;
            af[f] = *(const v8s*)(Ab + arow * 64 + ((g ^ ((arow >> 1) & 3)) << 4));
            int brow = wc * 64 + f * 16 + q16;
            bf[f] = *(const v8s*)(Bb + brow * 64 + ((g ^ ((brow >> 1) & 3)) << 4));
        }
#pragma unroll
        for (int i = 0; i < 4; i++)
#pragma unroll
            for (int j = 0; j < 4; j++)
                acc[i][j] = __builtin_amdgcn_mfma_f32_16x16x32_bf16(af[i], bf[j], acc[i][j], 0, 0, 0);
        __syncthreads();
    }

    const float QSCL = 0.125f * 1.44269504088896340736f;
#pragma unroll
    for (int i = 0; i < 4; i++)
#pragma unroll
        for (int j = 0; j < 4; j++)
#pragma unroll
            for (int r = 0; r < 4; r++) {
                int gr = mtile * 128 + wr * 64 + i * 16 + 4 * g + r;
                int gcl = col0 + wc * 64 + j * 16 + q16;       // col within this matrix's 768
                int b = gr / NN, n = gr % NN;
                int h = gcl / DH, d = gcl % DH;
                int bh = b * NH + h;
                float v = acc[i][j][r] + bias[gcl];
                if (mat == 0)      q[(bh * NN + n) * DH + d]  = f2bf(v * QSCL);
                else if (mat == 1) k[(bh * NN + n) * DH + d]  = f2bf(v);
                else               vT[(bh * DH + d) * NN + n] = f2bf(v);
            }
}

// ---- flash attention: LDS-staged K/V tiles (double-buffered, swizzled), swapped-operand MFMA ----
__global__ __launch_bounds__(256) void attn_k(
    const unsigned short* __restrict__ q, const unsigned short* __restrict__ k,
    const unsigned short* __restrict__ vT, unsigned short* __restrict__ z) {
    __shared__ unsigned short Kbuf[2][64 * 64];
    __shared__ unsigned short Vbuf[2][64 * 64];
    __shared__ unsigned short plds[4][16][72];

    int bh = blockIdx.x % 24;
    int qt = blockIdx.x / 24;
    int b = bh / NH, h = bh % NH;
    int w = threadIdx.x >> 6, l = threadIdx.x & 63;
    int q16 = l & 15, g = l >> 4;
    const unsigned short* qp = q + (size_t)bh * NN * DH;
    const unsigned short* kp = k + (size_t)bh * NN * DH;
    const unsigned short* vp = vT + (size_t)bh * DH * NN;
    int qrow = qt * 64 + w * 16 + q16;

    v8s qf0 = *(const v8s*)(qp + qrow * DH + 8 * g);
    v8s qf1 = *(const v8s*)(qp + qrow * DH + 32 + 8 * g);

    int sY = w * 2048 + l * 16;
    int srow0 = sY >> 7;
    int ss = (sY >> 4) & 7;

    auto stage = [&](int t, int buf) {
        int kv = t * 64;
#pragma unroll
        for (int i = 0; i < 2; ++i) {
            int row = srow0 + i * 8;
            int c16 = ss ^ (row & 7);
            char* kdst = (char*)&Kbuf[buf][0] + w * 2048 + i * 1024;
            char* vdst = (char*)&Vbuf[buf][0] + w * 2048 + i * 1024;
            glds16(kp + (kv + row) * DH + (c16 << 3), kdst);
            glds16(vp + row * NN + kv + (c16 << 3), vdst);
        }
    };

    v4f zero = {0.f, 0.f, 0.f, 0.f};
    float mrow = -INFINITY, lsum = 0.f;
    v4f o[4];
#pragma unroll
    for (int dt = 0; dt < 4; dt++) o[dt] = zero;

    stage(0, 0);
    __syncthreads();

    for (int t = 0; t < NN / 64; ++t) {
        int cur = t & 1;
        if (t + 1 < NN / 64) stage(t + 1, cur ^ 1);

        const char* kb = (const char*)&Kbuf[cur][0];
        const char* vb = (const char*)&Vbuf[cur][0];

        v4f st[4];
#pragma unroll
        for (int ct = 0; ct < 4; ct++) {
            int krow = ct * 16 + q16;
            v8s kf0 = *(const v8s*)(kb + krow * 128 + ((g ^ (krow & 7)) << 4));
            v8s kf1 = *(const v8s*)(kb + krow * 128 + (((4 + g) ^ (krow & 7)) << 4));
            st[ct] = __builtin_amdgcn_mfma_f32_16x16x32_bf16(kf0, qf0, zero, 0, 0, 0);
            st[ct] = __builtin_amdgcn_mfma_f32_16x16x32_bf16(kf1, qf1, st[ct], 0, 0, 0);
        }

        float vmax = fmaxf(fmaxf(fmaxf(st[0][0], st[0][1]), fmaxf(st[0][2], st[0][3])),
                           fmaxf(fmaxf(st[1][0], st[1][1]), fmaxf(st[1][2], st[1][3])));
        vmax = fmaxf(vmax, fmaxf(fmaxf(fmaxf(st[2][0], st[2][1]), fmaxf(st[2][2], st[2][3])),
                                 fmaxf(fmaxf(st[3][0], st[3][1]), fmaxf(st[3][2], st[3][3]))));
        vmax = fmaxf(vmax, __shfl_xor(vmax, 16));
        vmax = fmaxf(vmax, __shfl_xor(vmax, 32));
        float mn = fmaxf(mrow, vmax);
        float sc = exp2f(mrow - mn);
        float rs = 0.f;
#pragma unroll
        for (int ct = 0; ct < 4; ct++) {
            float p0 = exp2f(st[ct][0] - mn);
            float p1 = exp2f(st[ct][1] - mn);
            float p2 = exp2f(st[ct][2] - mn);
            float p3 = exp2f(st[ct][3] - mn);
            rs += (p0 + p1) + (p2 + p3);
            short4 pk;
            pk.x = (short)f2bf(p0); pk.y = (short)f2bf(p1);
            pk.z = (short)f2bf(p2); pk.w = (short)f2bf(p3);
            *(short4*)(&plds[w][q16][ct * 16 + 4 * g]) = pk;
        }
        rs += __shfl_xor(rs, 16);
        rs += __shfl_xor(rs, 32);
        lsum = lsum * sc + rs;
        mrow = mn;
#pragma unroll
        for (int dt = 0; dt < 4; dt++)
#pragma unroll
            for (int r = 0; r < 4; r++) o[dt][r] *= sc;

        v8s pf0 = *(const v8s*)(&plds[w][q16][8 * g]);
        v8s pf1 = *(const v8s*)(&plds[w][q16][32 + 8 * g]);
#pragma unroll
        for (int dt = 0; dt < 4; dt++) {
            int dcol = dt * 16 + q16;
            v8s vf0 = *(const v8s*)(vb + dcol * 128 + ((g ^ (dcol & 7)) << 4));
            v8s vf1 = *(const v8s*)(vb + dcol * 128 + (((4 + g) ^ (dcol & 7)) << 4));
            o[dt] = __builtin_amdgcn_mfma_f32_16x16x32_bf16(vf0, pf0, o[dt], 0, 0, 0);
            o[dt] = __builtin_amdgcn_mfma_f32_16x16x32_bf16(vf1, pf1, o[dt], 0, 0, 0);
        }
        __syncthreads();
    }

    float inv = 1.f / lsum;
    int n = qt * 64 + w * 16 + q16;
#pragma unroll
    for (int dt = 0; dt < 4; dt++) {
        short4 s4;
        s4.x = (short)f2bf(o[dt][0] * inv);
        s4.y = (short)f2bf(o[dt][1] * inv);
        s4.z = (short)f2bf(o[dt][2] * inv);
        s4.w = (short)f2bf(o[dt][3] * inv);
        *(short4*)(&z[((size_t)(b * NN + n)) * DM + h * DH + dt * 16 + 4 * g]) = s4;
    }
}

// ---- output projection: z[4096,768] @ wo + bo -> fp32; same tiled structure ----
__global__ __launch_bounds__(256) void out_gemm_k(
    const unsigned short* __restrict__ zb, const unsigned short* __restrict__ woT,
    const float* __restrict__ bo, float* __restrict__ out) {
    __shared__ unsigned short Abuf[2][128 * 32];
    __shared__ unsigned short Bbuf[2][128 * 32];

    int ctile = blockIdx.x;              // 0..5
    int mtile = blockIdx.y;              // 0..31
    int col0 = ctile * 128;

    int tid = threadIdx.x;
    int w = tid >> 6, l = tid & 63;
    int q16 = l & 15, g = l >> 4;
    int wr = w >> 1, wc = w & 1;

    int srow0 = tid >> 2;
    int ss = tid & 3;

    auto stage = [&](int tt, int buf) {
        int k0 = tt * 32;
#pragma unroll
        for (int i = 0; i < 2; ++i) {
            int row = srow0 + i * 64;
            int c16 = ss ^ ((row >> 1) & 3);
            glds16(zb + (mtile * 128 + row) * 768 + k0 + (c16 << 3),
                   (char*)&Abuf[buf][0] + i * 4096 + tid * 16);
            glds16(woT + (col0 + row) * 768 + k0 + (c16 << 3),
                   (char*)&Bbuf[buf][0] + i * 4096 + tid * 16);
        }
    };

    v4f zero = {0.f, 0.f, 0.f, 0.f};
    v4f acc[4][4];
#pragma unroll
    for (int i = 0; i < 4; i++)
#pragma unroll
        for (int j = 0; j < 4; j++) acc[i][j] = zero;

    stage(0, 0);
    __syncthreads();

    for (int tt = 0; tt < 24; ++tt) {
        int cur = tt & 1;
        if (tt + 1 < 24) stage(tt + 1, cur ^ 1);
        const char* Ab = (const char*)&Abuf[cur][0];
        const char* Bb = (const char*)&Bbuf[cur][0];
        v8s af[4], bf[4];
#pragma unroll
        for (int f = 0; f < 4; f++) {
            int arow = wr * 64 + f * 16 + q16;
            af[f] = *(const v8s*)(Ab + arow * 64 + ((g ^ ((arow >> 1) & 3)) << 4));
            int brow = wc * 64 + f * 16 + q16;
            bf[f] = *(const v8s*)(Bb + brow * 64 + ((g ^ ((brow >> 1) & 3)) << 4));
        }
#pragma unroll
        for (int i = 0; i < 4; i++)
#pragma unroll
            for (int j = 0; j < 4; j++)
                acc[i][j] = __builtin_amdgcn_mfma_f32_16x16x32_bf16(af[i], bf[j], acc[i][j], 0, 0, 0);
        __syncthreads();
    }

#pragma unroll
    for (int i = 0; i < 4; i++)
#pragma unroll
        for (int j = 0; j < 4; j++)
#pragma unroll
            for (int r = 0; r < 4; r++) {
                int gr = mtile * 128 + wr * 64 + i * 16 + 4 * g + r;
                int gc = col0 + wc * 64 + j * 16 + q16;
                out[gr * 768 + gc] = acc[i][j][r] + bo[gc];
            }
}

extern "C" void kernel_launch(void* const* d_in, const int* in_sizes, int n_in,
                              void* d_out, int out_size, void* d_ws, size_t ws_size,
                              hipStream_t stream) {
    const float* x  = (const float*)d_in[0];
    const float* wq = (const float*)d_in[1];
    const float* bq = (const float*)d_in[2];
    const float* wk = (const float*)d_in[3];
    const float* bk = (const float*)d_in[4];
    const float* wv = (const float*)d_in[5];
    const float* bv = (const float*)d_in[6];
    const float* wo = (const float*)d_in[7];
    const float* bo = (const float*)d_in[8];
    float* out = (float*)d_out;

    const int NX = BB * NN * DM;
    const int NW = 768 * 768;

    unsigned short* wsp = (unsigned short*)d_ws;
    unsigned short* xb  = wsp;
    unsigned short* wqT = xb + NX;
    unsigned short* wkT = wqT + NW;
    unsigned short* wvT = wkT + NW;
    unsigned short* woT = wvT + NW;
    unsigned short* qb  = woT + NW;
    unsigned short* kb  = qb + NX;
    unsigned short* vTb = kb + NX;
    unsigned short* zb  = vTb + NX;

    cast_x_k<<<NX / (256 * 4), 256, 0, stream>>>(x, xb, NX);
    cast_wT_k<<<dim3(144, 4), 256, 0, stream>>>(wq, wk, wv, wo, wqT, wkT, wvT, woT);
    qkv_gemm_k<<<dim3(18, 32), 256, 0, stream>>>(xb, wqT, wkT, wvT, bq, bk, bv, qb, kb, vTb);
    attn_k<<<BB * NH * (NN / 64), 256, 0, stream>>>(qb, kb, vTb, zb);
    out_gemm_k<<<dim3(6, 32), 256, 0, stream>>>(zb, woT, bo, out);
}